// Round 3
// baseline (806.730 us; speedup 1.0000x reference)
//
#include <hip/hip_runtime.h>

// B=4, H=W=64, N=4096, C=512, HEAD=8, dh=64, SR=4, Nk=256
// Split-bf16 MFMA: A'=[hi|lo] per row (1024 cols), logical K'=1536 with
//   A section map: kk<512 -> hi(kk); kk<1024 -> lo(kk); else hi(kk-1024)
//   B section map: kk<512 -> hi(kk); kk<1024 -> hi(kk-512); else lo(kk-512)
// giving aH*bH + aL*bH + aH*bL (drops only aL*bL ~ 4e-6 rel).

typedef __bf16 bf16x8 __attribute__((ext_vector_type(8)));
typedef float f32x4 __attribute__((ext_vector_type(4)));

__device__ __forceinline__ ushort f2bf(float v) {
  uint u = __float_as_uint(v);
  return (ushort)((u + 0x7FFFu + ((u >> 16) & 1u)) >> 16);
}
__device__ __forceinline__ float bf2f(ushort h) {
  return __uint_as_float((uint)h << 16);
}

// ---------------- conversions ----------------
// x [16384][512] f32 -> x' [16384][1024] bf16 (hi|lo)
__global__ __launch_bounds__(256) void convert_x_kernel(
    const float* __restrict__ x, ushort* __restrict__ xq, int rows) {
  int gid = blockIdx.x * 256 + threadIdx.x;  // rows*64
  int row = gid >> 6, c8 = (gid & 63) << 3;
  if (row >= rows) return;
  float4 a = *(const float4*)(x + (size_t)row * 512 + c8);
  float4 b = *(const float4*)(x + (size_t)row * 512 + c8 + 4);
  ushort h[8], l[8];
  float vv[8] = {a.x, a.y, a.z, a.w, b.x, b.y, b.z, b.w};
#pragma unroll
  for (int e = 0; e < 8; ++e) {
    h[e] = f2bf(vv[e]);
    l[e] = f2bf(vv[e] - bf2f(h[e]));
  }
  uint4 hp, lp;
  hp.x = h[0] | ((uint)h[1] << 16); hp.y = h[2] | ((uint)h[3] << 16);
  hp.z = h[4] | ((uint)h[5] << 16); hp.w = h[6] | ((uint)h[7] << 16);
  lp.x = l[0] | ((uint)l[1] << 16); lp.y = l[2] | ((uint)l[3] << 16);
  lp.z = l[4] | ((uint)l[5] << 16); lp.w = l[6] | ((uint)l[7] << 16);
  *(uint4*)(xq + (size_t)row * 1024 + c8) = hp;
  *(uint4*)(xq + (size_t)row * 1024 + 512 + c8) = lp;
}

// Wq/Wp/Wk/Wv [512][512] -> split [n][1024]; Wk->Wkv rows 0-511, Wv->512-1023
__global__ __launch_bounds__(256) void convert_w_kernel(
    const float* __restrict__ Wq, const float* __restrict__ Wp,
    const float* __restrict__ Wk, const float* __restrict__ Wv,
    ushort* __restrict__ Wq_, ushort* __restrict__ Wp_,
    ushort* __restrict__ Wkv_) {
  int z = blockIdx.y;
  const float* src = (z == 0) ? Wq : (z == 1) ? Wp : (z == 2) ? Wk : Wv;
  ushort* dst = (z == 0) ? Wq_ : (z == 1) ? Wp_ : (z == 2) ? Wkv_ : (Wkv_ + 512 * 1024);
  int gid = blockIdx.x * 256 + threadIdx.x;  // 512*64
  int row = gid >> 6, c8 = (gid & 63) << 3;
  float4 a = *(const float4*)(src + (size_t)row * 512 + c8);
  float4 b = *(const float4*)(src + (size_t)row * 512 + c8 + 4);
  ushort h[8], l[8];
  float vv[8] = {a.x, a.y, a.z, a.w, b.x, b.y, b.z, b.w};
#pragma unroll
  for (int e = 0; e < 8; ++e) {
    h[e] = f2bf(vv[e]);
    l[e] = f2bf(vv[e] - bf2f(h[e]));
  }
  uint4 hp, lp;
  hp.x = h[0] | ((uint)h[1] << 16); hp.y = h[2] | ((uint)h[3] << 16);
  hp.z = h[4] | ((uint)h[5] << 16); hp.w = h[6] | ((uint)h[7] << 16);
  lp.x = l[0] | ((uint)l[1] << 16); lp.y = l[2] | ((uint)l[3] << 16);
  lp.z = l[4] | ((uint)l[5] << 16); lp.w = l[6] | ((uint)l[7] << 16);
  *(uint4*)(dst + (size_t)row * 1024 + c8) = hp;
  *(uint4*)(dst + (size_t)row * 1024 + 512 + c8) = lp;
}

// Wsr [kh][kw][ci][co] -> Wsr' [khw][co][1024(ci hi|lo)] (transpose ci<->co)
__global__ void convert_wsr_kernel(const float* __restrict__ Wsr,
                                   ushort* __restrict__ Wsr_) {
  __shared__ float t[32][33];
  int z = blockIdx.z;               // khw chunk
  int ci0 = blockIdx.y * 32, co0 = blockIdx.x * 32;
  int tx = threadIdx.x, ty = threadIdx.y;  // 32 x 8
#pragma unroll
  for (int i = 0; i < 32; i += 8)
    t[ty + i][tx] = Wsr[((size_t)z * 512 + ci0 + ty + i) * 512 + co0 + tx];
  __syncthreads();
#pragma unroll
  for (int i = 0; i < 32; i += 8) {
    float v = t[tx][ty + i];               // = W[ci0+tx][co0+ty+i]
    int co = co0 + ty + i, ci = ci0 + tx;
    ushort h = f2bf(v), l = f2bf(v - bf2f(h));
    Wsr_[((size_t)z * 512 + co) * 1024 + ci] = h;
    Wsr_[((size_t)z * 512 + co) * 1024 + 512 + ci] = l;
  }
}

__global__ void concat_bias_kernel(const float* __restrict__ bk,
                                   const float* __restrict__ bv,
                                   float* __restrict__ bkv) {
  int t = threadIdx.x;  // 512
  bkv[t] = bk[t];
  bkv[512 + t] = bv[t];
}

// ---------------- shared MFMA GEMM body: 128x128 tile, BK=64, 4 waves ----------------
// A',B' split-bf16 [rows][1024]; logical K'=1536 (24 K-steps).
// LDS layout [row][64] bf16 with XOR swizzle: ushort idx = row*64 + (k8 ^ (row&7))*8
__device__ __forceinline__ void gemm_body_k1536(
    const ushort* __restrict__ A, const ushort* __restrict__ Bw,
    const float* __restrict__ bias, float* __restrict__ C,
    int N, int bx, int by) {
  __shared__ __align__(16) ushort As[128 * 64];
  __shared__ __align__(16) ushort Bs[128 * 64];
  int tid = threadIdx.x;
  int lane = tid & 63, w = tid >> 6;
  int wr = w >> 1, wc = w & 1;
  int trow = tid >> 3, tk8 = tid & 7;

  const ushort* aRow[4];
  const ushort* bRow[4];
#pragma unroll
  for (int it = 0; it < 4; ++it) {
    aRow[it] = A + (size_t)(by * 128 + it * 32 + trow) * 1024;
    bRow[it] = Bw + (size_t)(bx * 128 + it * 32 + trow) * 1024;
  }
  int wIdx = trow * 64 + ((tk8 ^ (trow & 7)) << 3);

  f32x4 acc[4][4];
#pragma unroll
  for (int i = 0; i < 4; ++i)
#pragma unroll
    for (int j = 0; j < 4; ++j) acc[i][j] = (f32x4){0.f, 0.f, 0.f, 0.f};

  for (int ks = 0; ks < 24; ++ks) {
    int kk = ks * 64 + tk8 * 8;
    int ap = kk - (kk >= 1024 ? 1024 : 0);
    int bp_ = kk - (kk >= 512 ? 512 : 0);
    uint4 ra[4], rb[4];
#pragma unroll
    for (int it = 0; it < 4; ++it) ra[it] = *(const uint4*)(aRow[it] + ap);
#pragma unroll
    for (int it = 0; it < 4; ++it) rb[it] = *(const uint4*)(bRow[it] + bp_);
    __syncthreads();
#pragma unroll
    for (int it = 0; it < 4; ++it) {
      *(uint4*)&As[wIdx + it * 2048] = ra[it];
      *(uint4*)&Bs[wIdx + it * 2048] = rb[it];
    }
    __syncthreads();
#pragma unroll
    for (int kk2 = 0; kk2 < 2; ++kk2) {
      int rk = (kk2 * 32 + ((lane >> 4) << 3)) ^ ((lane & 7) << 3);
      bf16x8 af[4], bg[4];
#pragma unroll
      for (int i = 0; i < 4; ++i) {
        int row = wr * 64 + i * 16 + (lane & 15);
        af[i] = *(const bf16x8*)&As[row * 64 + rk];
      }
#pragma unroll
      for (int j = 0; j < 4; ++j) {
        int col = wc * 64 + j * 16 + (lane & 15);
        bg[j] = *(const bf16x8*)&Bs[col * 64 + rk];
      }
#pragma unroll
      for (int i = 0; i < 4; ++i)
#pragma unroll
        for (int j = 0; j < 4; ++j)
          acc[i][j] = __builtin_amdgcn_mfma_f32_16x16x32_bf16(af[i], bg[j], acc[i][j], 0, 0, 0);
    }
  }

#pragma unroll
  for (int j = 0; j < 4; ++j) {
    int col = bx * 128 + wc * 64 + j * 16 + (lane & 15);
    float bj = bias ? bias[col] : 0.f;
#pragma unroll
    for (int i = 0; i < 4; ++i) {
      int row0 = by * 128 + wr * 64 + i * 16 + ((lane >> 4) << 2);
#pragma unroll
      for (int r = 0; r < 4; ++r)
        C[(size_t)(row0 + r) * N + col] = acc[i][j][r] + bj;
    }
  }
}

// plain GEMM entry: grid (N/128, M/128)
__global__ __launch_bounds__(256) void gemm_k1536_kernel(
    const ushort* __restrict__ A, const ushort* __restrict__ Bw,
    const float* __restrict__ bias, float* __restrict__ C, int N) {
  gemm_body_k1536(A, Bw, bias, C, N, blockIdx.x, blockIdx.y);
}

// fused q-proj (512 blocks) + kv-proj (64 blocks), linear grid 576
__global__ __launch_bounds__(256) void proj_fused_kernel(
    const ushort* __restrict__ xq, const ushort* __restrict__ Wq_,
    const float* __restrict__ bq, float* __restrict__ qbuf,
    const ushort* __restrict__ xkv_, const ushort* __restrict__ Wkv_,
    const float* __restrict__ bkv, float* __restrict__ kvb) {
  int bid = blockIdx.x;
  if (bid < 512)
    gemm_body_k1536(xq, Wq_, bq, qbuf, 512, bid & 3, bid >> 2);
  else {
    int b2 = bid - 512;
    gemm_body_k1536(xkv_, Wkv_, bkv, kvb, 1024, b2 & 7, b2 >> 3);
  }
}

// ---------------- conv as split-8 MFMA GEMM ----------------
// blockIdx.z = chunk of 2 (kh,kw) taps; K''=3072 (48 steps); partials [8][1024][512]
__global__ __launch_bounds__(256) void conv_mfma_kernel(
    const ushort* __restrict__ xq, const ushort* __restrict__ Wsr_,
    float* __restrict__ part) {
  __shared__ __align__(16) ushort As[128 * 64];
  __shared__ __align__(16) ushort Bs[128 * 64];
  int tid = threadIdx.x;
  int bx = blockIdx.x, by = blockIdx.y, bz = blockIdx.z;
  int lane = tid & 63, w = tid >> 6;
  int wr = w >> 1, wc = w & 1;
  int trow = tid >> 3, tk8 = tid & 7;

  int xrow[4][2];
  const ushort* bRow[4];
#pragma unroll
  for (int it = 0; it < 4; ++it) {
    int gm = by * 128 + it * 32 + trow;
    int b_ = gm >> 8, oh = (gm >> 4) & 15, ow = gm & 15;
#pragma unroll
    for (int p = 0; p < 2; ++p) {
      int khw = bz * 2 + p, kh = khw >> 2, kw = khw & 3;
      xrow[it][p] = b_ * 4096 + (oh * 4 + kh) * 64 + ow * 4 + kw;
    }
    bRow[it] = Wsr_ + ((size_t)(bz * 2) * 512 + bx * 128 + it * 32 + trow) * 1024;
  }
  int wIdx = trow * 64 + ((tk8 ^ (trow & 7)) << 3);

  f32x4 acc[4][4];
#pragma unroll
  for (int i = 0; i < 4; ++i)
#pragma unroll
    for (int j = 0; j < 4; ++j) acc[i][j] = (f32x4){0.f, 0.f, 0.f, 0.f};

  for (int ks = 0; ks < 48; ++ks) {
    int kkg = ks * 64 + tk8 * 8;
    int p = (kkg >= 1536) ? 1 : 0;
    int kk = kkg - p * 1536;
    int ap = kk - (kk >= 1024 ? 1024 : 0);
    int bp_ = kk - (kk >= 512 ? 512 : 0);
    uint4 ra[4], rb[4];
#pragma unroll
    for (int it = 0; it < 4; ++it) {
      int xr = p ? xrow[it][1] : xrow[it][0];
      ra[it] = *(const uint4*)(xq + (size_t)xr * 1024 + ap);
    }
#pragma unroll
    for (int it = 0; it < 4; ++it)
      rb[it] = *(const uint4*)(bRow[it] + (size_t)p * 524288 + bp_);
    __syncthreads();
#pragma unroll
    for (int it = 0; it < 4; ++it) {
      *(uint4*)&As[wIdx + it * 2048] = ra[it];
      *(uint4*)&Bs[wIdx + it * 2048] = rb[it];
    }
    __syncthreads();
#pragma unroll
    for (int kk2 = 0; kk2 < 2; ++kk2) {
      int rk = (kk2 * 32 + ((lane >> 4) << 3)) ^ ((lane & 7) << 3);
      bf16x8 af[4], bg[4];
#pragma unroll
      for (int i = 0; i < 4; ++i) {
        int row = wr * 64 + i * 16 + (lane & 15);
        af[i] = *(const bf16x8*)&As[row * 64 + rk];
      }
#pragma unroll
      for (int j = 0; j < 4; ++j) {
        int col = wc * 64 + j * 16 + (lane & 15);
        bg[j] = *(const bf16x8*)&Bs[col * 64 + rk];
      }
#pragma unroll
      for (int i = 0; i < 4; ++i)
#pragma unroll
        for (int j = 0; j < 4; ++j)
          acc[i][j] = __builtin_amdgcn_mfma_f32_16x16x32_bf16(af[i], bg[j], acc[i][j], 0, 0, 0);
    }
  }

  float* Cp = part + (size_t)bz * 524288;
#pragma unroll
  for (int j = 0; j < 4; ++j) {
    int col = bx * 128 + wc * 64 + j * 16 + (lane & 15);
#pragma unroll
    for (int i = 0; i < 4; ++i) {
      int row0 = by * 128 + wr * 64 + i * 16 + ((lane >> 4) << 2);
#pragma unroll
      for (int r = 0; r < 4; ++r)
        Cp[(size_t)(row0 + r) * 512 + col] = acc[i][j][r];
    }
  }
}

// ---------------- partial-sum + bias + LayerNorm -> split-bf16 ----------------
__global__ __launch_bounds__(256) void ln_kernel(
    const float* __restrict__ part, const float* __restrict__ bsr,
    const float* __restrict__ gamma, const float* __restrict__ beta,
    ushort* __restrict__ xkv_) {
  int row = blockIdx.x;  // 0..1023
  int t = threadIdx.x;   // 256
  float v0 = bsr[t], v1 = bsr[t + 256];
  for (int p = 0; p < 8; ++p) {
    v0 += part[(size_t)p * 524288 + (size_t)row * 512 + t];
    v1 += part[(size_t)p * 524288 + (size_t)row * 512 + t + 256];
  }
  float s = v0 + v1, sq = v0 * v0 + v1 * v1;
#pragma unroll
  for (int o = 1; o < 64; o <<= 1) {
    s += __shfl_xor(s, o);
    sq += __shfl_xor(sq, o);
  }
  __shared__ float red[8];
  int wv = t >> 6;
  if ((t & 63) == 0) { red[wv] = s; red[4 + wv] = sq; }
  __syncthreads();
  s = red[0] + red[1] + red[2] + red[3];
  sq = red[4] + red[5] + red[6] + red[7];
  float mu = s * (1.0f / 512.0f);
  float var = sq * (1.0f / 512.0f) - mu * mu;
  float rs = rsqrtf(var + 1e-5f);
  float y0 = (v0 - mu) * rs * gamma[t] + beta[t];
  float y1 = (v1 - mu) * rs * gamma[t + 256] + beta[t + 256];
  ushort h0 = f2bf(y0), h1 = f2bf(y1);
  xkv_[(size_t)row * 1024 + t] = h0;
  xkv_[(size_t)row * 1024 + t + 256] = h1;
  xkv_[(size_t)row * 1024 + 512 + t] = f2bf(y0 - bf2f(h0));
  xkv_[(size_t)row * 1024 + 512 + t + 256] = f2bf(y1 - bf2f(h1));
}

// ---------------- fused attention (fp32, v2) -> split-bf16 output ----------------
__global__ __launch_bounds__(256) void attn_kernel(
    const float* __restrict__ q, const float* __restrict__ kv,
    ushort* __restrict__ attno) {
  __shared__ __align__(16) float qs[64 * 68];
  __shared__ __align__(16) float Ks[64 * 68];
  __shared__ __align__(16) float Vs[64 * 68];
  __shared__ __align__(16) float ps[64 * 68];
  int tid = threadIdx.x;
  int qt = blockIdx.x, h = blockIdx.y, b = blockIdx.z;
  int n0 = qt * 64;
  int ty = tid >> 4, tx = tid & 15;

#pragma unroll
  for (int i = 0; i < 4; ++i) {
    int idx = tid + i * 256;
    int r = idx >> 4, c4 = (idx & 15) << 2;
    float4 v = *(const float4*)(q + (size_t)(b * 4096 + n0 + r) * 512 + h * 64 + c4);
    v.x *= 0.125f; v.y *= 0.125f; v.z *= 0.125f; v.w *= 0.125f;
    *(float4*)&qs[r * 68 + c4] = v;
  }

  float m[4], l[4], o[4][4];
#pragma unroll
  for (int i = 0; i < 4; ++i) {
    m[i] = -1e30f; l[i] = 0.f;
#pragma unroll
    for (int j = 0; j < 4; ++j) o[i][j] = 0.f;
  }

  for (int qtr = 0; qtr < 4; ++qtr) {
    __syncthreads();
#pragma unroll
    for (int i = 0; i < 4; ++i) {
      int idx = tid + i * 256;
      int kr = idx >> 4, c4 = (idx & 15) << 2;
      const float* src = kv + (size_t)(b * 256 + qtr * 64 + kr) * 1024 + h * 64 + c4;
      *(float4*)&Ks[kr * 68 + c4] = *(const float4*)src;
      *(float4*)&Vs[kr * 68 + c4] = *(const float4*)(src + 512);
    }
    __syncthreads();

    float s[4][4] = {};
#pragma unroll
    for (int d4 = 0; d4 < 16; ++d4) {
      float4 kf[4];
#pragma unroll
      for (int j = 0; j < 4; ++j)
        kf[j] = *(float4*)&Ks[(tx + 16 * j) * 68 + d4 * 4];
#pragma unroll
      for (int i = 0; i < 4; ++i) {
        float4 qf = *(float4*)&qs[(ty + 16 * i) * 68 + d4 * 4];
#pragma unroll
        for (int j = 0; j < 4; ++j)
          s[i][j] += qf.x * kf[j].x + qf.y * kf[j].y + qf.z * kf[j].z + qf.w * kf[j].w;
      }
    }

#pragma unroll
    for (int i = 0; i < 4; ++i) {
      float qm = fmaxf(fmaxf(s[i][0], s[i][1]), fmaxf(s[i][2], s[i][3]));
#pragma unroll
      for (int d = 1; d < 16; d <<= 1) qm = fmaxf(qm, __shfl_xor(qm, d));
      float nm = fmaxf(m[i], qm);
      float f = __expf(m[i] - nm);
      float p0 = __expf(s[i][0] - nm);
      float p1 = __expf(s[i][1] - nm);
      float p2 = __expf(s[i][2] - nm);
      float p3 = __expf(s[i][3] - nm);
      float sum = p0 + p1 + p2 + p3;
#pragma unroll
      for (int d = 1; d < 16; d <<= 1) sum += __shfl_xor(sum, d);
      l[i] = l[i] * f + sum;
      m[i] = nm;
      o[i][0] *= f; o[i][1] *= f; o[i][2] *= f; o[i][3] *= f;
      float* pr = &ps[(ty + 16 * i) * 68];
      pr[tx] = p0; pr[tx + 16] = p1; pr[tx + 32] = p2; pr[tx + 48] = p3;
    }
    __syncthreads();

#pragma unroll
    for (int kc = 0; kc < 16; ++kc) {
      float4 vf[4];
#pragma unroll
      for (int j = 0; j < 4; ++j)
        vf[j] = *(float4*)&Vs[(kc * 4 + j) * 68 + tx * 4];
#pragma unroll
      for (int i = 0; i < 4; ++i) {
        float4 pf = *(float4*)&ps[(ty + 16 * i) * 68 + kc * 4];
        o[i][0] += pf.x * vf[0].x + pf.y * vf[1].x + pf.z * vf[2].x + pf.w * vf[3].x;
        o[i][1] += pf.x * vf[0].y + pf.y * vf[1].y + pf.z * vf[2].y + pf.w * vf[3].y;
        o[i][2] += pf.x * vf[0].z + pf.y * vf[1].z + pf.z * vf[2].z + pf.w * vf[3].z;
        o[i][3] += pf.x * vf[0].w + pf.y * vf[1].w + pf.z * vf[2].w + pf.w * vf[3].w;
      }
    }
  }

#pragma unroll
  for (int i = 0; i < 4; ++i) {
    float inv = 1.0f / l[i];
    float v0 = o[i][0] * inv, v1 = o[i][1] * inv, v2 = o[i][2] * inv, v3 = o[i][3] * inv;
    ushort h0 = f2bf(v0), h1 = f2bf(v1), h2 = f2bf(v2), h3 = f2bf(v3);
    uint2 ph, pl;
    ph.x = h0 | ((uint)h1 << 16); ph.y = h2 | ((uint)h3 << 16);
    pl.x = f2bf(v0 - bf2f(h0)) | ((uint)f2bf(v1 - bf2f(h1)) << 16);
    pl.y = f2bf(v2 - bf2f(h2)) | ((uint)f2bf(v3 - bf2f(h3)) << 16);
    size_t base = (size_t)(b * 4096 + n0 + ty + 16 * i) * 1024 + h * 64 + tx * 4;
    *(uint2*)(attno + base) = ph;
    *(uint2*)(attno + base + 512) = pl;
  }
}

// ---------------- launch ----------------
extern "C" void kernel_launch(void* const* d_in, const int* in_sizes, int n_in,
                              void* d_out, int out_size, void* d_ws, size_t ws_size,
                              hipStream_t stream) {
  const float* x     = (const float*)d_in[0];
  const float* Wq    = (const float*)d_in[1];
  const float* bq    = (const float*)d_in[2];
  const float* Wk    = (const float*)d_in[3];
  const float* bk    = (const float*)d_in[4];
  const float* Wv    = (const float*)d_in[5];
  const float* bv    = (const float*)d_in[6];
  const float* Wp    = (const float*)d_in[7];
  const float* bp    = (const float*)d_in[8];
  const float* Wsr   = (const float*)d_in[9];
  const float* bsr   = (const float*)d_in[10];
  const float* gamma = (const float*)d_in[11];
  const float* beta  = (const float*)d_in[12];

  float* ws = (float*)d_ws;
  // region A: x' then attno' (both 16384x1024 ushort = 8,388,608 floats)
  ushort* xq     = (ushort*)ws;
  ushort* attno_ = (ushort*)ws;
  // region B: conv_part(4,194,304 fl) + Wsr'(4,194,304 fl); later qbuf(8,388,608 fl)
  float*  regionB   = ws + 8388608;
  float*  conv_part = regionB;
  ushort* Wsr_      = (ushort*)(regionB + 4194304);
  float*  qbuf      = regionB;
  ushort* Wq_  = (ushort*)(ws + 16777216);
  ushort* Wp_  = (ushort*)(ws + 17039360);
  ushort* Wkv_ = (ushort*)(ws + 17301504);
  ushort* xkv_ = (ushort*)(ws + 17825792);
  float*  kvb  = ws + 18350080;
  float*  bkv  = ws + 19398656 - 1024;  // tail scratch? no -- use dedicated slot below
  // safer: put bkv right after kvb (kvb is 1,048,576 floats)
  bkv = ws + 18350080 + 1048576 - 0;  // == ws + 19398656; need 1024 floats
  float* outp = (float*)d_out;

  convert_x_kernel<<<4096, 256, 0, stream>>>(x, xq, 16384);
  convert_w_kernel<<<dim3(128, 4), 256, 0, stream>>>(Wq, Wp, Wk, Wv, Wq_, Wp_, Wkv_);
  convert_wsr_kernel<<<dim3(16, 16, 16), dim3(32, 8), 0, stream>>>(Wsr, Wsr_);
  concat_bias_kernel<<<1, 512, 0, stream>>>(bk, bv, bkv);
  conv_mfma_kernel<<<dim3(4, 8, 8), 256, 0, stream>>>(xq, Wsr_, conv_part);
  ln_kernel<<<1024, 256, 0, stream>>>(conv_part, bsr, gamma, beta, xkv_);
  proj_fused_kernel<<<576, 256, 0, stream>>>(xq, Wq_, bq, qbuf, xkv_, Wkv_, bkv, kvb);
  attn_kernel<<<dim3(64, 8, 4), 256, 0, stream>>>(qbuf, kvb, attno_);
  gemm_k1536_kernel<<<dim3(4, 128), 256, 0, stream>>>(attno_, Wp_, bp, outp, 512);
}

// Round 4
// 253.068 us; speedup vs baseline: 3.1878x; 3.1878x over previous
//
#include <hip/hip_runtime.h>

// B=4, H=W=64, N=4096, C=512, HEAD=8, dh=64, SR=4, Nk=256
// Split-bf16: val = hi + lo (both bf16). 3-term product drops only lo*lo (~4e-6 rel).

typedef __bf16 bf16x8 __attribute__((ext_vector_type(8)));
typedef float f32x4 __attribute__((ext_vector_type(4)));

__device__ __forceinline__ ushort f2bf(float v) {
  uint u = __float_as_uint(v);
  return (ushort)((u + 0x7FFFu + ((u >> 16) & 1u)) >> 16);
}
__device__ __forceinline__ float bf2f(ushort h) {
  return __uint_as_float((uint)h << 16);
}
__device__ __forceinline__ void gload16(const void* g, void* l) {
  __builtin_amdgcn_global_load_lds(
      (const __attribute__((address_space(1))) void*)g,
      (__attribute__((address_space(3))) void*)l, 16, 0, 0);
}

// ---------------- conversions ----------------
__global__ __launch_bounds__(256) void convert_x_kernel(
    const float* __restrict__ x, ushort* __restrict__ xq, int rows) {
  int gid = blockIdx.x * 256 + threadIdx.x;
  int row = gid >> 6, c8 = (gid & 63) << 3;
  if (row >= rows) return;
  float4 a = *(const float4*)(x + (size_t)row * 512 + c8);
  float4 b = *(const float4*)(x + (size_t)row * 512 + c8 + 4);
  ushort h[8], l[8];
  float vv[8] = {a.x, a.y, a.z, a.w, b.x, b.y, b.z, b.w};
#pragma unroll
  for (int e = 0; e < 8; ++e) { h[e] = f2bf(vv[e]); l[e] = f2bf(vv[e] - bf2f(h[e])); }
  uint4 hp, lp;
  hp.x = h[0] | ((uint)h[1] << 16); hp.y = h[2] | ((uint)h[3] << 16);
  hp.z = h[4] | ((uint)h[5] << 16); hp.w = h[6] | ((uint)h[7] << 16);
  lp.x = l[0] | ((uint)l[1] << 16); lp.y = l[2] | ((uint)l[3] << 16);
  lp.z = l[4] | ((uint)l[5] << 16); lp.w = l[6] | ((uint)l[7] << 16);
  *(uint4*)(xq + (size_t)row * 1024 + c8) = hp;
  *(uint4*)(xq + (size_t)row * 1024 + 512 + c8) = lp;
}

__global__ __launch_bounds__(256) void convert_w_kernel(
    const float* __restrict__ Wq, const float* __restrict__ Wp,
    const float* __restrict__ Wk, const float* __restrict__ Wv,
    ushort* __restrict__ Wq_, ushort* __restrict__ Wp_,
    ushort* __restrict__ Wkv_) {
  int z = blockIdx.y;
  const float* src = (z == 0) ? Wq : (z == 1) ? Wp : (z == 2) ? Wk : Wv;
  ushort* dst = (z == 0) ? Wq_ : (z == 1) ? Wp_ : (z == 2) ? Wkv_ : (Wkv_ + 512 * 1024);
  int gid = blockIdx.x * 256 + threadIdx.x;
  int row = gid >> 6, c8 = (gid & 63) << 3;
  float4 a = *(const float4*)(src + (size_t)row * 512 + c8);
  float4 b = *(const float4*)(src + (size_t)row * 512 + c8 + 4);
  ushort h[8], l[8];
  float vv[8] = {a.x, a.y, a.z, a.w, b.x, b.y, b.z, b.w};
#pragma unroll
  for (int e = 0; e < 8; ++e) { h[e] = f2bf(vv[e]); l[e] = f2bf(vv[e] - bf2f(h[e])); }
  uint4 hp, lp;
  hp.x = h[0] | ((uint)h[1] << 16); hp.y = h[2] | ((uint)h[3] << 16);
  hp.z = h[4] | ((uint)h[5] << 16); hp.w = h[6] | ((uint)h[7] << 16);
  lp.x = l[0] | ((uint)l[1] << 16); lp.y = l[2] | ((uint)l[3] << 16);
  lp.z = l[4] | ((uint)l[5] << 16); lp.w = l[6] | ((uint)l[7] << 16);
  *(uint4*)(dst + (size_t)row * 1024 + c8) = hp;
  *(uint4*)(dst + (size_t)row * 1024 + 512 + c8) = lp;
}

__global__ void convert_wsr_kernel(const float* __restrict__ Wsr,
                                   ushort* __restrict__ Wsr_) {
  __shared__ float t[32][33];
  int z = blockIdx.z;
  int ci0 = blockIdx.y * 32, co0 = blockIdx.x * 32;
  int tx = threadIdx.x, ty = threadIdx.y;
#pragma unroll
  for (int i = 0; i < 32; i += 8)
    t[ty + i][tx] = Wsr[((size_t)z * 512 + ci0 + ty + i) * 512 + co0 + tx];
  __syncthreads();
#pragma unroll
  for (int i = 0; i < 32; i += 8) {
    float v = t[tx][ty + i];
    int co = co0 + ty + i, ci = ci0 + tx;
    ushort h = f2bf(v), l = f2bf(v - bf2f(h));
    Wsr_[((size_t)z * 512 + co) * 1024 + ci] = h;
    Wsr_[((size_t)z * 512 + co) * 1024 + 512 + ci] = l;
  }
}

__global__ void concat_bias_kernel(const float* __restrict__ bk,
                                   const float* __restrict__ bv,
                                   float* __restrict__ bkv) {
  int t = threadIdx.x;
  bkv[t] = bk[t];
  bkv[512 + t] = bv[t];
}

// ---------------- MFMA GEMM (m97 structure): gload_lds + pre-swizzled source ----------
// A',B' split-bf16 [rows][1024]; logical K'=1536.
// EPI=0: C fp32 [M][N] + bias. EPI=1: q-split per-head layout + scale 0.125.
template <int EPI>
__device__ __forceinline__ void gemm_body(
    const ushort* __restrict__ A, const ushort* __restrict__ Bw,
    const float* __restrict__ bias, float* __restrict__ C,
    ushort* __restrict__ Qs, int N, int bx, int by) {
  __shared__ __align__(16) ushort As[128 * 64];
  __shared__ __align__(16) ushort Bs[128 * 64];
  int tid = threadIdx.x;
  int lane = tid & 63, w = tid >> 6;
  int wr = w >> 1, wc = w & 1;
  int l15 = lane & 15, g = lane >> 4;
  int srow = lane >> 3;
  int scol = (lane & 7) ^ srow;  // pre-swizzled source block

  const ushort* aBase = A + (size_t)(by * 128 + w * 32 + srow) * 1024 + scol * 8;
  const ushort* bBase = Bw + (size_t)(bx * 128 + w * 32 + srow) * 1024 + scol * 8;
  ushort* aDst = &As[w * 32 * 64];
  ushort* bDst = &Bs[w * 32 * 64];

  f32x4 acc[4][4];
#pragma unroll
  for (int i = 0; i < 4; ++i)
#pragma unroll
    for (int j = 0; j < 4; ++j) acc[i][j] = (f32x4){0.f, 0.f, 0.f, 0.f};

  for (int ks = 0; ks < 24; ++ks) {
    int kk = ks * 64;
    int ap = kk - (kk >= 1024 ? 1024 : 0);
    int bp = kk - (kk >= 512 ? 512 : 0);
#pragma unroll
    for (int t = 0; t < 4; ++t) {
      gload16(aBase + (size_t)t * 8192 + ap, aDst + t * 512);
      gload16(bBase + (size_t)t * 8192 + bp, bDst + t * 512);
    }
    __syncthreads();
#pragma unroll
    for (int kk2 = 0; kk2 < 2; ++kk2) {
      int rb = kk2 * 4 + g;
      bf16x8 af[4], bg[4];
#pragma unroll
      for (int i = 0; i < 4; ++i) {
        int row = wr * 64 + i * 16 + l15;
        af[i] = *(const bf16x8*)&As[row * 64 + ((rb ^ (row & 7)) << 3)];
      }
#pragma unroll
      for (int j = 0; j < 4; ++j) {
        int col = wc * 64 + j * 16 + l15;
        bg[j] = *(const bf16x8*)&Bs[col * 64 + ((rb ^ (col & 7)) << 3)];
      }
#pragma unroll
      for (int i = 0; i < 4; ++i)
#pragma unroll
        for (int j = 0; j < 4; ++j)
          acc[i][j] = __builtin_amdgcn_mfma_f32_16x16x32_bf16(af[i], bg[j], acc[i][j], 0, 0, 0);
    }
    __syncthreads();
  }

  if (EPI == 0) {
#pragma unroll
    for (int j = 0; j < 4; ++j) {
      int col = bx * 128 + wc * 64 + j * 16 + l15;
      float bj = bias ? bias[col] : 0.f;
#pragma unroll
      for (int i = 0; i < 4; ++i) {
        int row0 = by * 128 + wr * 64 + i * 16 + g * 4;
#pragma unroll
        for (int r = 0; r < 4; ++r)
          C[(size_t)(row0 + r) * N + col] = acc[i][j][r] + bj;
      }
    }
  } else {
#pragma unroll
    for (int j = 0; j < 4; ++j) {
      int col = bx * 128 + wc * 64 + j * 16 + l15;  // < 512
      float bj = bias[col];
      int hh = col >> 6, d = col & 63;
#pragma unroll
      for (int i = 0; i < 4; ++i) {
        int row0 = by * 128 + wr * 64 + i * 16 + g * 4;
#pragma unroll
        for (int r = 0; r < 4; ++r) {
          float v = (acc[i][j][r] + bj) * 0.125f;
          ushort h = f2bf(v), lo = f2bf(v - bf2f(h));
          size_t base = ((size_t)(row0 + r) * 8 + hh) * 128 + d;
          Qs[base] = h;
          Qs[base + 64] = lo;
        }
      }
    }
  }
}

__global__ __launch_bounds__(256) void gemm_f32_kernel(
    const ushort* __restrict__ A, const ushort* __restrict__ Bw,
    const float* __restrict__ bias, float* __restrict__ C, int N) {
  gemm_body<0>(A, Bw, bias, C, nullptr, N, blockIdx.x, blockIdx.y);
}

__global__ __launch_bounds__(256) void gemm_qsplit_kernel(
    const ushort* __restrict__ A, const ushort* __restrict__ Bw,
    const float* __restrict__ bias, ushort* __restrict__ Qs) {
  gemm_body<1>(A, Bw, bias, nullptr, Qs, 512, blockIdx.x, blockIdx.y);
}

// ---------------- conv as split-K MFMA GEMM (gload_lds version) ----------------
__global__ __launch_bounds__(256) void conv_mfma_kernel(
    const ushort* __restrict__ xq, const ushort* __restrict__ Wsr_,
    float* __restrict__ part) {
  __shared__ __align__(16) ushort As[128 * 64];
  __shared__ __align__(16) ushort Bs[128 * 64];
  int tid = threadIdx.x;
  int bx = blockIdx.x, by = blockIdx.y, bz = blockIdx.z;
  int lane = tid & 63, w = tid >> 6;
  int wr = w >> 1, wc = w & 1;
  int l15 = lane & 15, g = lane >> 4;
  int srow = lane >> 3;
  int scol = (lane & 7) ^ srow;

  int xrb[4];
#pragma unroll
  for (int t = 0; t < 4; ++t) {
    int gm = by * 128 + w * 32 + t * 8 + srow;
    xrb[t] = (gm >> 8) * 4096 + (((gm >> 4) & 15) << 8) + ((gm & 15) << 2);
  }
  const ushort* bBase =
      Wsr_ + ((size_t)(bz * 2) * 512 + bx * 128 + w * 32 + srow) * 1024 + scol * 8;
  ushort* aDst = &As[w * 32 * 64];
  ushort* bDst = &Bs[w * 32 * 64];

  f32x4 acc[4][4];
#pragma unroll
  for (int i = 0; i < 4; ++i)
#pragma unroll
    for (int j = 0; j < 4; ++j) acc[i][j] = (f32x4){0.f, 0.f, 0.f, 0.f};

  for (int ks = 0; ks < 48; ++ks) {
    int p = (ks >= 24) ? 1 : 0;
    int kk = (ks - p * 24) * 64;
    int ap = kk - (kk >= 1024 ? 1024 : 0);
    int bp = kk - (kk >= 512 ? 512 : 0);
    int khw = bz * 2 + p;
    int xoff = ((khw >> 2) << 6) + (khw & 3);  // kh*64+kw
#pragma unroll
    for (int t = 0; t < 4; ++t) {
      gload16(xq + (size_t)(xrb[t] + xoff) * 1024 + ap + scol * 8, aDst + t * 512);
      gload16(bBase + (size_t)p * 524288 + (size_t)t * 8192 + bp, bDst + t * 512);
    }
    __syncthreads();
#pragma unroll
    for (int kk2 = 0; kk2 < 2; ++kk2) {
      int rb = kk2 * 4 + g;
      bf16x8 af[4], bg[4];
#pragma unroll
      for (int i = 0; i < 4; ++i) {
        int row = wr * 64 + i * 16 + l15;
        af[i] = *(const bf16x8*)&As[row * 64 + ((rb ^ (row & 7)) << 3)];
      }
#pragma unroll
      for (int j = 0; j < 4; ++j) {
        int col = wc * 64 + j * 16 + l15;
        bg[j] = *(const bf16x8*)&Bs[col * 64 + ((rb ^ (col & 7)) << 3)];
      }
#pragma unroll
      for (int i = 0; i < 4; ++i)
#pragma unroll
        for (int j = 0; j < 4; ++j)
          acc[i][j] = __builtin_amdgcn_mfma_f32_16x16x32_bf16(af[i], bg[j], acc[i][j], 0, 0, 0);
    }
    __syncthreads();
  }

  float* Cp = part + (size_t)bz * 524288;
#pragma unroll
  for (int j = 0; j < 4; ++j) {
    int col = bx * 128 + wc * 64 + j * 16 + l15;
#pragma unroll
    for (int i = 0; i < 4; ++i) {
      int row0 = by * 128 + wr * 64 + i * 16 + g * 4;
#pragma unroll
      for (int r = 0; r < 4; ++r)
        Cp[(size_t)(row0 + r) * 512 + col] = acc[i][j][r];
    }
  }
}

// ---------------- partial-sum + bias + LayerNorm -> split-bf16 ----------------
__global__ __launch_bounds__(256) void ln_kernel(
    const float* __restrict__ part, const float* __restrict__ bsr,
    const float* __restrict__ gamma, const float* __restrict__ beta,
    ushort* __restrict__ xkv_) {
  int row = blockIdx.x;
  int t = threadIdx.x;
  float v0 = bsr[t], v1 = bsr[t + 256];
  for (int p = 0; p < 8; ++p) {
    v0 += part[(size_t)p * 524288 + (size_t)row * 512 + t];
    v1 += part[(size_t)p * 524288 + (size_t)row * 512 + t + 256];
  }
  float s = v0 + v1, sq = v0 * v0 + v1 * v1;
#pragma unroll
  for (int o = 1; o < 64; o <<= 1) {
    s += __shfl_xor(s, o);
    sq += __shfl_xor(sq, o);
  }
  __shared__ float red[8];
  int wv = t >> 6;
  if ((t & 63) == 0) { red[wv] = s; red[4 + wv] = sq; }
  __syncthreads();
  s = red[0] + red[1] + red[2] + red[3];
  sq = red[4] + red[5] + red[6] + red[7];
  float mu = s * (1.0f / 512.0f);
  float var = sq * (1.0f / 512.0f) - mu * mu;
  float rs = rsqrtf(var + 1e-5f);
  float y0 = (v0 - mu) * rs * gamma[t] + beta[t];
  float y1 = (v1 - mu) * rs * gamma[t + 256] + beta[t + 256];
  ushort h0 = f2bf(y0), h1 = f2bf(y1);
  xkv_[(size_t)row * 1024 + t] = h0;
  xkv_[(size_t)row * 1024 + t + 256] = h1;
  xkv_[(size_t)row * 1024 + 512 + t] = f2bf(y0 - bf2f(h0));
  xkv_[(size_t)row * 1024 + 512 + t + 256] = f2bf(y1 - bf2f(h1));
}

// ---------------- kv prep: kvb fp32 -> Kq split [bh][256][128], Vt split [bh][64][512]
__global__ __launch_bounds__(256) void kvprep_kernel(
    const float* __restrict__ kvb, ushort* __restrict__ Kq,
    ushort* __restrict__ Vt) {
  int gid = blockIdx.x * 256 + threadIdx.x;  // 131072
  int row = gid >> 7, c8 = (gid & 127) << 3;
  int b = row >> 8, kk = row & 255;
  float4 a = *(const float4*)(kvb + (size_t)row * 1024 + c8);
  float4 bb = *(const float4*)(kvb + (size_t)row * 1024 + c8 + 4);
  float vv[8] = {a.x, a.y, a.z, a.w, bb.x, bb.y, bb.z, bb.w};
  ushort h[8], l[8];
#pragma unroll
  for (int e = 0; e < 8; ++e) { h[e] = f2bf(vv[e]); l[e] = f2bf(vv[e] - bf2f(h[e])); }
  if (c8 < 512) {
    int hh = c8 >> 6, d = c8 & 63;
    uint4 hp, lp;
    hp.x = h[0] | ((uint)h[1] << 16); hp.y = h[2] | ((uint)h[3] << 16);
    hp.z = h[4] | ((uint)h[5] << 16); hp.w = h[6] | ((uint)h[7] << 16);
    lp.x = l[0] | ((uint)l[1] << 16); lp.y = l[2] | ((uint)l[3] << 16);
    lp.z = l[4] | ((uint)l[5] << 16); lp.w = l[6] | ((uint)l[7] << 16);
    size_t base = ((size_t)((b * 8 + hh) * 256) + kk) * 128 + d;
    *(uint4*)(Kq + base) = hp;
    *(uint4*)(Kq + base + 64) = lp;
  } else {
    int c = c8 - 512;
    int hh = c >> 6, d0 = c & 63;
#pragma unroll
    for (int jj = 0; jj < 8; ++jj) {
      size_t base = ((size_t)((b * 8 + hh) * 64) + d0 + jj) * 512 + kk;
      Vt[base] = h[jj];
      Vt[base + 256] = l[jj];
    }
  }
}

// ---------------- MFMA flash attention ----------------
// Block = (qb, h, b): 64 q-rows, 4 waves (wave w: q-rows w*16..+15), chunks of 64 k.
// Swapped QK^T: S^T = mfma(K, Q): lane's column = its q (lane&15) -> softmax lane-local.
// PV: out^T = mfma(Vt, P^T): D col = q -> rescale/normalize lane-local.
__global__ __launch_bounds__(256) void attn_kernel(
    const ushort* __restrict__ Qs, const ushort* __restrict__ Kq,
    const ushort* __restrict__ Vt, ushort* __restrict__ attno) {
  __shared__ __align__(16) char arena[16384 + 16384 + 8192];
  ushort* KsL = (ushort*)arena;            // [64 kk][128: hi|lo], swizzled
  ushort* VtL = (ushort*)(arena + 16384);  // [64 d][128: hi|lo kk], swizzled
  ushort* PL = (ushort*)(arena + 32768);   // [64 q][64 kk] bf16, swizzled
  float* ob = (float*)arena;               // [64 d][68 q] epilogue alias

  int tid = threadIdx.x;
  int qb = blockIdx.x, h = blockIdx.y, b = blockIdx.z;
  int n0 = qb * 64, bh = b * 8 + h;
  int lane = tid & 63, w = tid >> 6;
  int q15 = lane & 15, g = lane >> 4;
  int qrow = w * 16 + q15;

  // Q fragments direct from global (held all kernel)
  const ushort* qptr = Qs + ((size_t)(b * 4096 + n0 + qrow) * 8 + h) * 128;
  bf16x8 qf[2][2];
#pragma unroll
  for (int s = 0; s < 2; ++s)
#pragma unroll
    for (int kb = 0; kb < 2; ++kb)
      qf[s][kb] = *(const bf16x8*)(qptr + s * 64 + kb * 32 + g * 8);

  f32x4 accO[4];
#pragma unroll
  for (int t = 0; t < 4; ++t) accO[t] = (f32x4){0.f, 0.f, 0.f, 0.f};
  float m = -1e30f, l = 0.f;

  const ushort* kbase = Kq + (size_t)bh * 256 * 128;
  const ushort* vbase = Vt + (size_t)bh * 64 * 512;

  for (int c = 0; c < 4; ++c) {
    __syncthreads();
    // stage K chunk [64 kk][128] and V chunk [64 d][128], XOR-swizzled
#pragma unroll
    for (int i = 0; i < 4; ++i) {
      int idx = tid + i * 256;
      int r = idx >> 4, blk = idx & 15;
      uint4 kv4 = *(const uint4*)(kbase + (size_t)(c * 64 + r) * 128 + blk * 8);
      *(uint4*)&KsL[r * 128 + ((blk ^ (r & 7)) << 3)] = kv4;
      uint4 vv4 = *(const uint4*)(vbase + (size_t)r * 512 + ((blk >> 3) << 8) +
                                  c * 64 + ((blk & 7) << 3));
      *(uint4*)&VtL[r * 128 + ((blk ^ (r & 7)) << 3)] = vv4;
    }
    __syncthreads();

    // S^T = Khi*Qhi + Khi*Qlo + Klo*Qhi
    f32x4 accS[4];
#pragma unroll
    for (int t = 0; t < 4; ++t) accS[t] = (f32x4){0.f, 0.f, 0.f, 0.f};
#pragma unroll
    for (int kb = 0; kb < 2; ++kb) {
      bf16x8 ak[4];
#pragma unroll
      for (int t = 0; t < 4; ++t) {
        int kkr = t * 16 + q15;
        ak[t] = *(const bf16x8*)&KsL[kkr * 128 + (((kb * 4 + g) ^ (kkr & 7)) << 3)];
      }
#pragma unroll
      for (int t = 0; t < 4; ++t)
        accS[t] = __builtin_amdgcn_mfma_f32_16x16x32_bf16(ak[t], qf[0][kb], accS[t], 0, 0, 0);
#pragma unroll
      for (int t = 0; t < 4; ++t)
        accS[t] = __builtin_amdgcn_mfma_f32_16x16x32_bf16(ak[t], qf[1][kb], accS[t], 0, 0, 0);
#pragma unroll
      for (int t = 0; t < 4; ++t) {
        int kkr = t * 16 + q15;
        bf16x8 al = *(const bf16x8*)&KsL[kkr * 128 + (((8 + kb * 4 + g) ^ (kkr & 7)) << 3)];
        accS[t] = __builtin_amdgcn_mfma_f32_16x16x32_bf16(al, qf[0][kb], accS[t], 0, 0, 0);
      }
    }

    // online softmax (all lane-local for q = lane&15; reduce across the 4 g-groups)
    float mx = -1e30f;
#pragma unroll
    for (int t = 0; t < 4; ++t)
#pragma unroll
      for (int r = 0; r < 4; ++r) mx = fmaxf(mx, accS[t][r]);
    mx = fmaxf(mx, __shfl_xor(mx, 16));
    mx = fmaxf(mx, __shfl_xor(mx, 32));
    float mn = fmaxf(m, mx);
    float fac = __expf(m - mn);
    m = mn;
    float sum = 0.f;
    ushort ph[4][4];
#pragma unroll
    for (int t = 0; t < 4; ++t)
#pragma unroll
      for (int r = 0; r < 4; ++r) {
        float p = __expf(accS[t][r] - mn);
        ushort hp = f2bf(p);
        ph[t][r] = hp;
        sum += bf2f(hp);  // l matches bf16 P used in PV
      }
    sum += __shfl_xor(sum, 16);
    sum += __shfl_xor(sum, 32);
    l = l * fac + sum;
#pragma unroll
    for (int t = 0; t < 4; ++t) {
      accO[t][0] *= fac; accO[t][1] *= fac; accO[t][2] *= fac; accO[t][3] *= fac;
    }
    // write P (bf16 pairs), swizzled
#pragma unroll
    for (int t = 0; t < 4; ++t)
#pragma unroll
      for (int rp = 0; rp < 4; rp += 2) {
        uint u = ph[t][rp] | ((uint)ph[t][rp + 1] << 16);
        int kkl = t * 16 + g * 4 + rp;
        int blk = kkl >> 3, off = kkl & 7;
        *(uint*)((char*)PL + qrow * 128 + ((blk ^ (q15 & 7)) << 4) + off * 2) = u;
      }
    __syncthreads();

    // PV: out^T += Vhi*P^T + Vlo*P^T
    bf16x8 pf[2];
#pragma unroll
    for (int kb = 0; kb < 2; ++kb)
      pf[kb] = *(const bf16x8*)((char*)PL + qrow * 128 + (((kb * 4 + g) ^ (q15 & 7)) << 4));
#pragma unroll
    for (int s = 0; s < 2; ++s)
#pragma unroll
      for (int kb = 0; kb < 2; ++kb)
#pragma unroll
        for (int t = 0; t < 4; ++t) {
          int d = t * 16 + q15;
          bf16x8 vf =
              *(const bf16x8*)&VtL[d * 128 + (((s * 8 + kb * 4 + g) ^ (d & 7)) << 3)];
          accO[t] = __builtin_amdgcn_mfma_f32_16x16x32_bf16(vf, pf[kb], accO[t], 0, 0, 0);
        }
  }

  // normalize + transpose via LDS + coalesced split-bf16 store
  float inv = 1.0f / l;
  __syncthreads();
#pragma unroll
  for (int t = 0; t < 4; ++t)
#pragma unroll
    for (int r = 0; r < 4; ++r)
      ob[(t * 16 + g * 4 + r) * 68 + qrow] = accO[t][r] * inv;
  __syncthreads();
#pragma unroll
  for (int i = 0; i < 2; ++i) {
    int idx = tid + i * 256;
    int qq = idx >> 3, d8 = (idx & 7) << 3;
    ushort hh[8], ll[8];
#pragma unroll
    for (int jj = 0; jj < 8; ++jj) {
      float v = ob[(d8 + jj) * 68 + qq];
      hh[jj] = f2bf(v);
      ll[jj] = f2bf(v - bf2f(hh[jj]));
    }
    uint4 hp, lp;
    hp.x = hh[0] | ((uint)hh[1] << 16); hp.y = hh[2] | ((uint)hh[3] << 16);
    hp.z = hh[4] | ((uint)hh[5] << 16); hp.w = hh[6] | ((uint)hh[7] << 16);
    lp.x = ll[0] | ((uint)ll[1] << 16); lp.y = ll[2] | ((uint)ll[3] << 16);
    lp.z = ll[4] | ((uint)ll[5] << 16); lp.w = ll[6] | ((uint)ll[7] << 16);
    size_t rowb = (size_t)(b * 4096 + n0 + qq) * 1024 + h * 64 + d8;
    *(uint4*)(attno + rowb) = hp;
    *(uint4*)(attno + rowb + 512) = lp;
  }
}

// ---------------- launch ----------------
extern "C" void kernel_launch(void* const* d_in, const int* in_sizes, int n_in,
                              void* d_out, int out_size, void* d_ws, size_t ws_size,
                              hipStream_t stream) {
  const float* x     = (const float*)d_in[0];
  const float* Wq    = (const float*)d_in[1];
  const float* bq    = (const float*)d_in[2];
  const float* Wk    = (const float*)d_in[3];
  const float* bk    = (const float*)d_in[4];
  const float* Wv    = (const float*)d_in[5];
  const float* bv    = (const float*)d_in[6];
  const float* Wp    = (const float*)d_in[7];
  const float* bp    = (const float*)d_in[8];
  const float* Wsr   = (const float*)d_in[9];
  const float* bsr   = (const float*)d_in[10];
  const float* gamma = (const float*)d_in[11];
  const float* beta  = (const float*)d_in[12];

  float* ws = (float*)d_ws;
  // region A (8,388,608 fl): x' split; later attno' split
  ushort* xq     = (ushort*)ws;
  ushort* attno_ = (ushort*)ws;
  // region B (8,388,608 fl): conv_part + Wsr'; later Qsplit
  float*  regionB   = ws + 8388608;
  float*  conv_part = regionB;                           // 4,194,304 fl
  ushort* Wsr_      = (ushort*)(regionB + 4194304);      // 8,388,608 us
  ushort* Qsplit    = (ushort*)regionB;                  // 16,777,216 us
  ushort* Wq_  = (ushort*)(ws + 16777216);
  ushort* Wp_  = (ushort*)(ws + 17039360);
  ushort* Wkv_ = (ushort*)(ws + 17301504);
  ushort* xkv_ = (ushort*)(ws + 17825792);
  float*  kvb  = ws + 18350080;            // 1,048,576 fl
  float*  bkv  = ws + 19398656;            // 1,024 fl
  ushort* Kq   = (ushort*)(ws + 19399680); // 1,048,576 us
  ushort* Vt   = (ushort*)(ws + 19923968); // 1,048,576 us
  float* outp = (float*)d_out;

  convert_x_kernel<<<4096, 256, 0, stream>>>(x, xq, 16384);
  convert_w_kernel<<<dim3(128, 4), 256, 0, stream>>>(Wq, Wp, Wk, Wv, Wq_, Wp_, Wkv_);
  convert_wsr_kernel<<<dim3(16, 16, 16), dim3(32, 8), 0, stream>>>(Wsr, Wsr_);
  concat_bias_kernel<<<1, 512, 0, stream>>>(bk, bv, bkv);
  conv_mfma_kernel<<<dim3(4, 8, 8), 256, 0, stream>>>(xq, Wsr_, conv_part);
  ln_kernel<<<1024, 256, 0, stream>>>(conv_part, bsr, gamma, beta, xkv_);
  gemm_qsplit_kernel<<<dim3(4, 128), 256, 0, stream>>>(xq, Wq_, bq, Qsplit);
  gemm_f32_kernel<<<dim3(8, 8), 256, 0, stream>>>(xkv_, Wkv_, bkv, kvb, 1024);
  kvprep_kernel<<<512, 256, 0, stream>>>(kvb, Kq, Vt);
  attn_kernel<<<dim3(64, 8, 4), 256, 0, stream>>>(Qsplit, Kq, Vt, attno_);
  gemm_f32_kernel<<<dim3(4, 128), 256, 0, stream>>>(attno_, Wp_, bp, outp, 512);
}

// Round 5
// 213.605 us; speedup vs baseline: 3.7767x; 1.1847x over previous
//
#include <hip/hip_runtime.h>

// B=4, H=W=64, N=4096, C=512, HEAD=8, dh=64, SR=4, Nk=256
// Split-bf16: val = hi + lo (both bf16). 3-term product drops only lo*lo (~4e-6 rel).

typedef __bf16 bf16x8 __attribute__((ext_vector_type(8)));
typedef float f32x4 __attribute__((ext_vector_type(4)));

__device__ __forceinline__ ushort f2bf(float v) {
  uint u = __float_as_uint(v);
  return (ushort)((u + 0x7FFFu + ((u >> 16) & 1u)) >> 16);
}
__device__ __forceinline__ float bf2f(ushort h) {
  return __uint_as_float((uint)h << 16);
}
__device__ __forceinline__ void gload16(const void* g, void* l) {
  __builtin_amdgcn_global_load_lds(
      (const __attribute__((address_space(1))) void*)g,
      (__attribute__((address_space(3))) void*)l, 16, 0, 0);
}
// bijective XCD swizzle for nwg % 8 == 0: work-ids contiguous per XCD
__device__ __forceinline__ int xcd_swz(int bid, int nwg) {
  int cpx = nwg >> 3;
  return (bid & 7) * cpx + (bid >> 3);
}

// ---------------- fused prep: convert x, W's, Wsr, biases ----------------
__global__ __launch_bounds__(256) void prep_kernel(
    const float* __restrict__ x, const float* __restrict__ Wq,
    const float* __restrict__ Wp, const float* __restrict__ Wk,
    const float* __restrict__ Wv, const float* __restrict__ Wsr,
    const float* __restrict__ bk, const float* __restrict__ bv,
    ushort* __restrict__ xq, ushort* __restrict__ Wq_,
    ushort* __restrict__ Wp_, ushort* __restrict__ Wkv_,
    ushort* __restrict__ Wsr_, float* __restrict__ bkv) {
  __shared__ float t[32][33];
  int bid = blockIdx.x, tid = threadIdx.x;
  if (bid < 4096 + 512) {
    const float* src;
    ushort* dst;
    int gid;
    if (bid < 4096) {  // x -> x' split
      src = x; dst = xq; gid = bid * 256 + tid;
    } else {
      int z = (bid - 4096) >> 7;
      src = (z == 0) ? Wq : (z == 1) ? Wp : (z == 2) ? Wk : Wv;
      dst = (z == 0) ? Wq_ : (z == 1) ? Wp_ : (z == 2) ? Wkv_ : (Wkv_ + 512 * 1024);
      gid = ((bid - 4096) & 127) * 256 + tid;
    }
    int row = gid >> 6, c8 = (gid & 63) << 3;
    float4 a = *(const float4*)(src + (size_t)row * 512 + c8);
    float4 b = *(const float4*)(src + (size_t)row * 512 + c8 + 4);
    ushort h[8], l[8];
    float vv[8] = {a.x, a.y, a.z, a.w, b.x, b.y, b.z, b.w};
#pragma unroll
    for (int e = 0; e < 8; ++e) { h[e] = f2bf(vv[e]); l[e] = f2bf(vv[e] - bf2f(h[e])); }
    uint4 hp, lp;
    hp.x = h[0] | ((uint)h[1] << 16); hp.y = h[2] | ((uint)h[3] << 16);
    hp.z = h[4] | ((uint)h[5] << 16); hp.w = h[6] | ((uint)h[7] << 16);
    lp.x = l[0] | ((uint)l[1] << 16); lp.y = l[2] | ((uint)l[3] << 16);
    lp.z = l[4] | ((uint)l[5] << 16); lp.w = l[6] | ((uint)l[7] << 16);
    *(uint4*)(dst + (size_t)row * 1024 + c8) = hp;
    *(uint4*)(dst + (size_t)row * 1024 + 512 + c8) = lp;
  } else if (bid < 4096 + 512 + 4096) {  // Wsr transpose+split
    int tb = bid - 4608;
    int z = tb >> 8, rem = tb & 255;
    int ci0 = (rem >> 4) << 5, co0 = (rem & 15) << 5;
    int tx = tid & 31, ty = tid >> 5;
#pragma unroll
    for (int i = 0; i < 32; i += 8)
      t[ty + i][tx] = Wsr[((size_t)z * 512 + ci0 + ty + i) * 512 + co0 + tx];
    __syncthreads();
#pragma unroll
    for (int i = 0; i < 32; i += 8) {
      float v = t[tx][ty + i];
      int co = co0 + ty + i, ci = ci0 + tx;
      ushort h = f2bf(v), l = f2bf(v - bf2f(h));
      Wsr_[((size_t)z * 512 + co) * 1024 + ci] = h;
      Wsr_[((size_t)z * 512 + co) * 1024 + 512 + ci] = l;
    }
  } else {  // bias concat
    bkv[tid] = bk[tid]; bkv[tid + 256] = bk[tid + 256];
    bkv[tid + 512] = bv[tid]; bkv[tid + 768] = bv[tid + 256];
  }
}

// ---------------- MFMA GEMM body (m97 structure) ----------------
// A',B' split-bf16 [rows][1024]; logical K'=1536.
// EPI=0: C fp32 [M][N] + bias. EPI=1: q-split per-head layout + scale 0.125.
template <int EPI>
__device__ __forceinline__ void gemm_body(
    const ushort* __restrict__ A, const ushort* __restrict__ Bw,
    const float* __restrict__ bias, float* __restrict__ C,
    ushort* __restrict__ Qs, int N, int bx, int by) {
  __shared__ __align__(16) ushort As[128 * 64];
  __shared__ __align__(16) ushort Bs[128 * 64];
  int tid = threadIdx.x;
  int lane = tid & 63, w = tid >> 6;
  int wr = w >> 1, wc = w & 1;
  int l15 = lane & 15, g = lane >> 4;
  int srow = lane >> 3;
  int scol = (lane & 7) ^ srow;  // pre-swizzled source block

  const ushort* aBase = A + (size_t)(by * 128 + w * 32 + srow) * 1024 + scol * 8;
  const ushort* bBase = Bw + (size_t)(bx * 128 + w * 32 + srow) * 1024 + scol * 8;
  ushort* aDst = &As[w * 32 * 64];
  ushort* bDst = &Bs[w * 32 * 64];

  f32x4 acc[4][4];
#pragma unroll
  for (int i = 0; i < 4; ++i)
#pragma unroll
    for (int j = 0; j < 4; ++j) acc[i][j] = (f32x4){0.f, 0.f, 0.f, 0.f};

  for (int ks = 0; ks < 24; ++ks) {
    int kk = ks * 64;
    int ap = kk - (kk >= 1024 ? 1024 : 0);
    int bp = kk - (kk >= 512 ? 512 : 0);
#pragma unroll
    for (int t = 0; t < 4; ++t) {
      gload16(aBase + (size_t)t * 8192 + ap, aDst + t * 512);
      gload16(bBase + (size_t)t * 8192 + bp, bDst + t * 512);
    }
    __syncthreads();
#pragma unroll
    for (int kk2 = 0; kk2 < 2; ++kk2) {
      int rb = kk2 * 4 + g;
      bf16x8 af[4], bg[4];
#pragma unroll
      for (int i = 0; i < 4; ++i) {
        int row = wr * 64 + i * 16 + l15;
        af[i] = *(const bf16x8*)&As[row * 64 + ((rb ^ (row & 7)) << 3)];
      }
#pragma unroll
      for (int j = 0; j < 4; ++j) {
        int col = wc * 64 + j * 16 + l15;
        bg[j] = *(const bf16x8*)&Bs[col * 64 + ((rb ^ (col & 7)) << 3)];
      }
#pragma unroll
      for (int i = 0; i < 4; ++i)
#pragma unroll
        for (int j = 0; j < 4; ++j)
          acc[i][j] = __builtin_amdgcn_mfma_f32_16x16x32_bf16(af[i], bg[j], acc[i][j], 0, 0, 0);
    }
    __syncthreads();
  }

  if (EPI == 0) {
#pragma unroll
    for (int j = 0; j < 4; ++j) {
      int col = bx * 128 + wc * 64 + j * 16 + l15;
      float bj = bias ? bias[col] : 0.f;
#pragma unroll
      for (int i = 0; i < 4; ++i) {
        int row0 = by * 128 + wr * 64 + i * 16 + g * 4;
#pragma unroll
        for (int r = 0; r < 4; ++r)
          C[(size_t)(row0 + r) * N + col] = acc[i][j][r] + bj;
      }
    }
  } else {
#pragma unroll
    for (int j = 0; j < 4; ++j) {
      int col = bx * 128 + wc * 64 + j * 16 + l15;  // < 512
      float bj = bias[col];
      int hh = col >> 6, d = col & 63;
#pragma unroll
      for (int i = 0; i < 4; ++i) {
        int row0 = by * 128 + wr * 64 + i * 16 + g * 4;
#pragma unroll
        for (int r = 0; r < 4; ++r) {
          float v = (acc[i][j][r] + bj) * 0.125f;
          ushort h = f2bf(v), lo = f2bf(v - bf2f(h));
          size_t base = ((size_t)(row0 + r) * 8 + hh) * 128 + d;
          Qs[base] = h;
          Qs[base + 64] = lo;
        }
      }
    }
  }
}

// fused q-proj (512 work-ids) + kv-proj (64 work-ids), XCD-swizzled
__global__ __launch_bounds__(256) void proj_fused_kernel(
    const ushort* __restrict__ xq, const ushort* __restrict__ Wq_,
    const float* __restrict__ bq, ushort* __restrict__ Qs,
    const ushort* __restrict__ xkv_, const ushort* __restrict__ Wkv_,
    const float* __restrict__ bkv, float* __restrict__ kvb) {
  int bid = xcd_swz(blockIdx.x, 576);
  if (bid < 512)
    gemm_body<1>(xq, Wq_, bq, nullptr, Qs, 512, bid & 3, bid >> 2);
  else {
    int b2 = bid - 512;
    gemm_body<0>(xkv_, Wkv_, bkv, kvb, nullptr, 1024, b2 & 7, b2 >> 3);
  }
}

// out-proj, XCD-swizzled
__global__ __launch_bounds__(256) void gemm_out_kernel(
    const ushort* __restrict__ A, const ushort* __restrict__ Bw,
    const float* __restrict__ bias, float* __restrict__ C) {
  int bid = xcd_swz(blockIdx.x, 512);
  gemm_body<0>(A, Bw, bias, C, nullptr, 512, bid & 3, bid >> 2);
}

// ---------------- conv as split-16 MFMA GEMM (one tap per z) ----------------
__global__ __launch_bounds__(256) void conv_mfma_kernel(
    const ushort* __restrict__ xq, const ushort* __restrict__ Wsr_,
    float* __restrict__ part) {
  __shared__ __align__(16) ushort As[128 * 64];
  __shared__ __align__(16) ushort Bs[128 * 64];
  int bid = xcd_swz(blockIdx.x, 512);
  int bx = bid & 3, by = (bid >> 2) & 7, z = bid >> 5;
  int kh = z >> 2, kw = z & 3;
  int tid = threadIdx.x;
  int lane = tid & 63, w = tid >> 6;
  int wr = w >> 1, wc = w & 1;
  int l15 = lane & 15, g = lane >> 4;
  int srow = lane >> 3;
  int scol = (lane & 7) ^ srow;

  const ushort* aBase[4];
#pragma unroll
  for (int t = 0; t < 4; ++t) {
    int gm = by * 128 + w * 32 + t * 8 + srow;
    int xr = (gm >> 8) * 4096 + ((((gm >> 4) & 15) << 2) + kh) * 64 +
             ((gm & 15) << 2) + kw;
    aBase[t] = xq + (size_t)xr * 1024 + scol * 8;
  }
  const ushort* bBase =
      Wsr_ + ((size_t)z * 512 + bx * 128 + w * 32 + srow) * 1024 + scol * 8;
  ushort* aDst = &As[w * 32 * 64];
  ushort* bDst = &Bs[w * 32 * 64];

  f32x4 acc[4][4];
#pragma unroll
  for (int i = 0; i < 4; ++i)
#pragma unroll
    for (int j = 0; j < 4; ++j) acc[i][j] = (f32x4){0.f, 0.f, 0.f, 0.f};

  for (int ks = 0; ks < 24; ++ks) {
    int kk = ks * 64;
    int ap = kk - (kk >= 1024 ? 1024 : 0);
    int bp = kk - (kk >= 512 ? 512 : 0);
#pragma unroll
    for (int t = 0; t < 4; ++t) {
      gload16(aBase[t] + ap, aDst + t * 512);
      gload16(bBase + (size_t)t * 8192 + bp, bDst + t * 512);
    }
    __syncthreads();
#pragma unroll
    for (int kk2 = 0; kk2 < 2; ++kk2) {
      int rb = kk2 * 4 + g;
      bf16x8 af[4], bg[4];
#pragma unroll
      for (int i = 0; i < 4; ++i) {
        int row = wr * 64 + i * 16 + l15;
        af[i] = *(const bf16x8*)&As[row * 64 + ((rb ^ (row & 7)) << 3)];
      }
#pragma unroll
      for (int j = 0; j < 4; ++j) {
        int col = wc * 64 + j * 16 + l15;
        bg[j] = *(const bf16x8*)&Bs[col * 64 + ((rb ^ (col & 7)) << 3)];
      }
#pragma unroll
      for (int i = 0; i < 4; ++i)
#pragma unroll
        for (int j = 0; j < 4; ++j)
          acc[i][j] = __builtin_amdgcn_mfma_f32_16x16x32_bf16(af[i], bg[j], acc[i][j], 0, 0, 0);
    }
    __syncthreads();
  }

  float* Cp = part + (size_t)z * 524288;
#pragma unroll
  for (int j = 0; j < 4; ++j) {
    int col = bx * 128 + wc * 64 + j * 16 + l15;
#pragma unroll
    for (int i = 0; i < 4; ++i) {
      int row0 = by * 128 + wr * 64 + i * 16 + g * 4;
#pragma unroll
      for (int r = 0; r < 4; ++r)
        Cp[(size_t)(row0 + r) * 512 + col] = acc[i][j][r];
    }
  }
}

// ---------------- partial-sum(16) + bias + LayerNorm -> split-bf16 ----------------
__global__ __launch_bounds__(256) void ln_kernel(
    const float* __restrict__ part, const float* __restrict__ bsr,
    const float* __restrict__ gamma, const float* __restrict__ beta,
    ushort* __restrict__ xkv_) {
  int row = blockIdx.x;
  int t = threadIdx.x;
  float v0 = bsr[t], v1 = bsr[t + 256];
  for (int p = 0; p < 16; ++p) {
    v0 += part[(size_t)p * 524288 + (size_t)row * 512 + t];
    v1 += part[(size_t)p * 524288 + (size_t)row * 512 + t + 256];
  }
  float s = v0 + v1, sq = v0 * v0 + v1 * v1;
#pragma unroll
  for (int o = 1; o < 64; o <<= 1) {
    s += __shfl_xor(s, o);
    sq += __shfl_xor(sq, o);
  }
  __shared__ float red[8];
  int wv = t >> 6;
  if ((t & 63) == 0) { red[wv] = s; red[4 + wv] = sq; }
  __syncthreads();
  s = red[0] + red[1] + red[2] + red[3];
  sq = red[4] + red[5] + red[6] + red[7];
  float mu = s * (1.0f / 512.0f);
  float var = sq * (1.0f / 512.0f) - mu * mu;
  float rs = rsqrtf(var + 1e-5f);
  float y0 = (v0 - mu) * rs * gamma[t] + beta[t];
  float y1 = (v1 - mu) * rs * gamma[t + 256] + beta[t + 256];
  ushort h0 = f2bf(y0), h1 = f2bf(y1);
  xkv_[(size_t)row * 1024 + t] = h0;
  xkv_[(size_t)row * 1024 + t + 256] = h1;
  xkv_[(size_t)row * 1024 + 512 + t] = f2bf(y0 - bf2f(h0));
  xkv_[(size_t)row * 1024 + 512 + t + 256] = f2bf(y1 - bf2f(h1));
}

// ---------------- kv prep: kvb fp32 -> Kq split [bh][256][128], Vt split [bh][64][512]
__global__ __launch_bounds__(256) void kvprep_kernel(
    const float* __restrict__ kvb, ushort* __restrict__ Kq,
    ushort* __restrict__ Vt) {
  int gid = blockIdx.x * 256 + threadIdx.x;  // 131072
  int row = gid >> 7, c8 = (gid & 127) << 3;
  int b = row >> 8, kk = row & 255;
  float4 a = *(const float4*)(kvb + (size_t)row * 1024 + c8);
  float4 bb = *(const float4*)(kvb + (size_t)row * 1024 + c8 + 4);
  float vv[8] = {a.x, a.y, a.z, a.w, bb.x, bb.y, bb.z, bb.w};
  ushort h[8], l[8];
#pragma unroll
  for (int e = 0; e < 8; ++e) { h[e] = f2bf(vv[e]); l[e] = f2bf(vv[e] - bf2f(h[e])); }
  if (c8 < 512) {
    int hh = c8 >> 6, d = c8 & 63;
    uint4 hp, lp;
    hp.x = h[0] | ((uint)h[1] << 16); hp.y = h[2] | ((uint)h[3] << 16);
    hp.z = h[4] | ((uint)h[5] << 16); hp.w = h[6] | ((uint)h[7] << 16);
    lp.x = l[0] | ((uint)l[1] << 16); lp.y = l[2] | ((uint)l[3] << 16);
    lp.z = l[4] | ((uint)l[5] << 16); lp.w = l[6] | ((uint)l[7] << 16);
    size_t base = ((size_t)((b * 8 + hh) * 256) + kk) * 128 + d;
    *(uint4*)(Kq + base) = hp;
    *(uint4*)(Kq + base + 64) = lp;
  } else {
    int c = c8 - 512;
    int hh = c >> 6, d0 = c & 63;
#pragma unroll
    for (int jj = 0; jj < 8; ++jj) {
      size_t base = ((size_t)((b * 8 + hh) * 64) + d0 + jj) * 512 + kk;
      Vt[base] = h[jj];
      Vt[base + 256] = l[jj];
    }
  }
}

// ---------------- MFMA flash attention ----------------
__global__ __launch_bounds__(256) void attn_kernel(
    const ushort* __restrict__ Qs, const ushort* __restrict__ Kq,
    const ushort* __restrict__ Vt, ushort* __restrict__ attno) {
  __shared__ __align__(16) char arena[16384 + 16384 + 8192];
  ushort* KsL = (ushort*)arena;            // [64 kk][128: hi|lo], swizzled
  ushort* VtL = (ushort*)(arena + 16384);  // [64 d][128: hi|lo kk], swizzled
  ushort* PL = (ushort*)(arena + 32768);   // [64 q][64 kk] bf16, swizzled
  float* ob = (float*)arena;               // [64 d][68 q] epilogue alias

  int tid = threadIdx.x;
  int qb = blockIdx.x, h = blockIdx.y, b = blockIdx.z;
  int n0 = qb * 64, bh = b * 8 + h;
  int lane = tid & 63, w = tid >> 6;
  int q15 = lane & 15, g = lane >> 4;
  int qrow = w * 16 + q15;

  const ushort* qptr = Qs + ((size_t)(b * 4096 + n0 + qrow) * 8 + h) * 128;
  bf16x8 qf[2][2];
#pragma unroll
  for (int s = 0; s < 2; ++s)
#pragma unroll
    for (int kb = 0; kb < 2; ++kb)
      qf[s][kb] = *(const bf16x8*)(qptr + s * 64 + kb * 32 + g * 8);

  f32x4 accO[4];
#pragma unroll
  for (int t = 0; t < 4; ++t) accO[t] = (f32x4){0.f, 0.f, 0.f, 0.f};
  float m = -1e30f, l = 0.f;

  const ushort* kbase = Kq + (size_t)bh * 256 * 128;
  const ushort* vbase = Vt + (size_t)bh * 64 * 512;

  for (int c = 0; c < 4; ++c) {
    __syncthreads();
#pragma unroll
    for (int i = 0; i < 4; ++i) {
      int idx = tid + i * 256;
      int r = idx >> 4, blk = idx & 15;
      uint4 kv4 = *(const uint4*)(kbase + (size_t)(c * 64 + r) * 128 + blk * 8);
      *(uint4*)&KsL[r * 128 + ((blk ^ (r & 7)) << 3)] = kv4;
      uint4 vv4 = *(const uint4*)(vbase + (size_t)r * 512 + ((blk >> 3) << 8) +
                                  c * 64 + ((blk & 7) << 3));
      *(uint4*)&VtL[r * 128 + ((blk ^ (r & 7)) << 3)] = vv4;
    }
    __syncthreads();

    f32x4 accS[4];
#pragma unroll
    for (int t = 0; t < 4; ++t) accS[t] = (f32x4){0.f, 0.f, 0.f, 0.f};
#pragma unroll
    for (int kb = 0; kb < 2; ++kb) {
      bf16x8 ak[4];
#pragma unroll
      for (int t = 0; t < 4; ++t) {
        int kkr = t * 16 + q15;
        ak[t] = *(const bf16x8*)&KsL[kkr * 128 + (((kb * 4 + g) ^ (kkr & 7)) << 3)];
      }
#pragma unroll
      for (int t = 0; t < 4; ++t)
        accS[t] = __builtin_amdgcn_mfma_f32_16x16x32_bf16(ak[t], qf[0][kb], accS[t], 0, 0, 0);
#pragma unroll
      for (int t = 0; t < 4; ++t)
        accS[t] = __builtin_amdgcn_mfma_f32_16x16x32_bf16(ak[t], qf[1][kb], accS[t], 0, 0, 0);
#pragma unroll
      for (int t = 0; t < 4; ++t) {
        int kkr = t * 16 + q15;
        bf16x8 al = *(const bf16x8*)&KsL[kkr * 128 + (((8 + kb * 4 + g) ^ (kkr & 7)) << 3)];
        accS[t] = __builtin_amdgcn_mfma_f32_16x16x32_bf16(al, qf[0][kb], accS[t], 0, 0, 0);
      }
    }

    float mx = -1e30f;
#pragma unroll
    for (int t = 0; t < 4; ++t)
#pragma unroll
      for (int r = 0; r < 4; ++r) mx = fmaxf(mx, accS[t][r]);
    mx = fmaxf(mx, __shfl_xor(mx, 16));
    mx = fmaxf(mx, __shfl_xor(mx, 32));
    float mn = fmaxf(m, mx);
    float fac = __expf(m - mn);
    m = mn;
    float sum = 0.f;
    ushort ph[4][4];
#pragma unroll
    for (int t = 0; t < 4; ++t)
#pragma unroll
      for (int r = 0; r < 4; ++r) {
        float p = __expf(accS[t][r] - mn);
        ushort hp = f2bf(p);
        ph[t][r] = hp;
        sum += bf2f(hp);
      }
    sum += __shfl_xor(sum, 16);
    sum += __shfl_xor(sum, 32);
    l = l * fac + sum;
#pragma unroll
    for (int t = 0; t < 4; ++t) {
      accO[t][0] *= fac; accO[t][1] *= fac; accO[t][2] *= fac; accO[t][3] *= fac;
    }
#pragma unroll
    for (int t = 0; t < 4; ++t)
#pragma unroll
      for (int rp = 0; rp < 4; rp += 2) {
        uint u = ph[t][rp] | ((uint)ph[t][rp + 1] << 16);
        int kkl = t * 16 + g * 4 + rp;
        int blk = kkl >> 3, off = kkl & 7;
        *(uint*)((char*)PL + qrow * 128 + ((blk ^ (q15 & 7)) << 4) + off * 2) = u;
      }
    __syncthreads();

    bf16x8 pf[2];
#pragma unroll
    for (int kb = 0; kb < 2; ++kb)
      pf[kb] = *(const bf16x8*)((char*)PL + qrow * 128 + (((kb * 4 + g) ^ (q15 & 7)) << 4));
#pragma unroll
    for (int s = 0; s < 2; ++s)
#pragma unroll
      for (int kb = 0; kb < 2; ++kb)
#pragma unroll
        for (int t = 0; t < 4; ++t) {
          int d = t * 16 + q15;
          bf16x8 vf =
              *(const bf16x8*)&VtL[d * 128 + (((s * 8 + kb * 4 + g) ^ (d & 7)) << 3)];
          accO[t] = __builtin_amdgcn_mfma_f32_16x16x32_bf16(vf, pf[kb], accO[t], 0, 0, 0);
        }
  }

  float inv = 1.0f / l;
  __syncthreads();
#pragma unroll
  for (int t = 0; t < 4; ++t)
#pragma unroll
    for (int r = 0; r < 4; ++r)
      ob[(t * 16 + g * 4 + r) * 68 + qrow] = accO[t][r] * inv;
  __syncthreads();
#pragma unroll
  for (int i = 0; i < 2; ++i) {
    int idx = tid + i * 256;
    int qq = idx >> 3, d8 = (idx & 7) << 3;
    ushort hh[8], ll[8];
#pragma unroll
    for (int jj = 0; jj < 8; ++jj) {
      float v = ob[(d8 + jj) * 68 + qq];
      hh[jj] = f2bf(v);
      ll[jj] = f2bf(v - bf2f(hh[jj]));
    }
    uint4 hp, lp;
    hp.x = hh[0] | ((uint)hh[1] << 16); hp.y = hh[2] | ((uint)hh[3] << 16);
    hp.z = hh[4] | ((uint)hh[5] << 16); hp.w = hh[6] | ((uint)hh[7] << 16);
    lp.x = ll[0] | ((uint)ll[1] << 16); lp.y = ll[2] | ((uint)ll[3] << 16);
    lp.z = ll[4] | ((uint)ll[5] << 16); lp.w = ll[6] | ((uint)ll[7] << 16);
    size_t rowb = (size_t)(b * 4096 + n0 + qq) * 1024 + h * 64 + d8;
    *(uint4*)(attno + rowb) = hp;
    *(uint4*)(attno + rowb + 512) = lp;
  }
}

// ---------------- launch ----------------
extern "C" void kernel_launch(void* const* d_in, const int* in_sizes, int n_in,
                              void* d_out, int out_size, void* d_ws, size_t ws_size,
                              hipStream_t stream) {
  const float* x     = (const float*)d_in[0];
  const float* Wq    = (const float*)d_in[1];
  const float* bq    = (const float*)d_in[2];
  const float* Wk    = (const float*)d_in[3];
  const float* bk    = (const float*)d_in[4];
  const float* Wv    = (const float*)d_in[5];
  const float* bv    = (const float*)d_in[6];
  const float* Wp    = (const float*)d_in[7];
  const float* bp    = (const float*)d_in[8];
  const float* Wsr   = (const float*)d_in[9];
  const float* bsr   = (const float*)d_in[10];
  const float* gamma = (const float*)d_in[11];
  const float* beta  = (const float*)d_in[12];

  float* ws = (float*)d_ws;
  // regionA (8,388,608 fl): xq (dies after proj launch); then attno_
  ushort* xq     = (ushort*)ws;
  ushort* attno_ = (ushort*)ws;
  // regionB (8,388,608 fl): conv_part [16][1024][512] f32; then Qsplit
  float*  conv_part = ws + 8388608;
  ushort* Qsplit    = (ushort*)(ws + 8388608);
  // shared tail (4,194,304 fl): Wsr_ (prep->conv); then kvb/bkv/Kq/Vt
  ushort* Wsr_ = (ushort*)(ws + 16777216);
  float*  kvb  = ws + 16777216;             // 1,048,576 fl
  float*  bkv  = ws + 17825792;             // 1,024 fl
  ushort* Kq   = (ushort*)(ws + 17826816);  // 1,048,576 us
  ushort* Vt   = (ushort*)(ws + 18351104);  // 1,048,576 us
  // weights + xkv_
  ushort* Wq_  = (ushort*)(ws + 20971520);
  ushort* Wp_  = (ushort*)(ws + 21233664);
  ushort* Wkv_ = (ushort*)(ws + 21495808);
  ushort* xkv_ = (ushort*)(ws + 22020096);
  float* outp = (float*)d_out;

  // NOTE: bkv overlaps Wsr_ region but prep writes both -> keep bkv AFTER kvb
  // (kvb written by proj launch, after conv consumed Wsr_; bkv written by prep
  //  would be clobbered... so bkv must NOT alias Wsr_. Move bkv to weight area.)
  bkv = ws + 22544384;  // 1,024 fl, dedicated

  prep_kernel<<<8705, 256, 0, stream>>>(x, Wq, Wp, Wk, Wv, Wsr, bk, bv,
                                        xq, Wq_, Wp_, Wkv_, Wsr_, bkv);
  conv_mfma_kernel<<<512, 256, 0, stream>>>(xq, Wsr_, conv_part);
  ln_kernel<<<1024, 256, 0, stream>>>(conv_part, bsr, gamma, beta, xkv_);
  proj_fused_kernel<<<576, 256, 0, stream>>>(xq, Wq_, bq, Qsplit, xkv_, Wkv_, bkv, kvb);
  kvprep_kernel<<<512, 256, 0, stream>>>(kvb, Kq, Vt);
  attn_kernel<<<dim3(64, 8, 4), 256, 0, stream>>>(Qsplit, Kq, Vt, attno_);
  gemm_out_kernel<<<512, 256, 0, stream>>>(attno_, Wp_, bp, outp);
}